// Round 1
// baseline (258.734 us; speedup 1.0000x reference)
//
#include <hip/hip_runtime.h>

// CenterLoss: loss = (1/B) * sum_j [ sum_{i: l_i=j} ||f_i - c_j||^2 / (n_j * D) ]
// B=65536, D=512, C=1000, fp32 in / fp32 scalar out. Memory-bound (134 MiB read,
// roofline ~21 us @ 6.3 TB/s).
//
// v2 theory: v1 (191.9 us) was bound by contended device-scope fp32 atomics:
// 131072 RMWs onto ~126 cache lines (~1040 serialized RMWs/line at the
// coherence point). Fix: 64 privatized copies of the accumulator arrays
// (wave_id & 63 picks the copy) -> ~16 RMWs/line. Plus grid-stride at 2048
// blocks (8 waves/SIMD device-wide) so each wave amortizes label-load latency
// over 8 samples.

#define WAVE 64
#define CPAD 1024           // padded per-class stride (>= nclass=1000)
#define MAX_COPIES 64       // power of two; 64 * 2 * CPAD * 4B = 512 KB workspace

// One wave per sample (grid-strided). Lanes cooperatively load the sample row +
// its center row as float4 (coalesced, 16B/lane), butterfly-reduce the squared
// distance, lane 0 atomically accumulates into its wave's private copy of the
// per-class sum/count arrays.
__global__ __launch_bounds__(256) void center_dist_kernel(
    const float* __restrict__ features,   // [batch, feat]
    const float* __restrict__ centers,    // [nclass, feat]
    const int*   __restrict__ labels,     // [batch]
    float* __restrict__ ws,               // [ncopy][2][CPAD]: sums then counts
    int batch, int feat, int ncopy)       // ncopy is a power of two
{
    const int wave_in_block = threadIdx.x >> 6;          // 0..3
    const int lane          = threadIdx.x & 63;
    const int wave_id       = blockIdx.x * 4 + wave_in_block;
    const int nwaves        = gridDim.x * 4;

    // Private accumulator copy for this wave: spreads atomic traffic over
    // ncopy * ~126 cache lines instead of ~126.
    float* __restrict__ my = ws + (size_t)(wave_id & (ncopy - 1)) * (2 * CPAD);

    const int n4 = feat >> 2;                            // 128 float4 per row

    for (int sample = wave_id; sample < batch; sample += nwaves) {
        const int label = labels[sample];
        const float4* __restrict__ f4 =
            (const float4*)(features + (size_t)sample * feat);
        const float4* __restrict__ c4 =
            (const float4*)(centers + (size_t)label * feat);

        float acc = 0.0f;
#pragma unroll 2
        for (int idx = lane; idx < n4; idx += WAVE) {
            float4 fv = f4[idx];
            float4 cv = c4[idx];
            float dx = fv.x - cv.x;
            float dy = fv.y - cv.y;
            float dz = fv.z - cv.z;
            float dw = fv.w - cv.w;
            acc += dx * dx + dy * dy;
            acc += dz * dz + dw * dw;
        }

        // wave-64 butterfly reduce
#pragma unroll
        for (int off = 32; off > 0; off >>= 1)
            acc += __shfl_down(acc, off, WAVE);

        if (lane == 0) {
            atomicAdd(&my[label], acc);
            atomicAdd(&my[CPAD + label], 1.0f);
        }
    }
}

// Single-block reduction: collapse the ncopy privatized copies per class, then
// per_class = sum / (count * feat), total / batch.
__global__ __launch_bounds__(256) void center_finalize_kernel(
    const float* __restrict__ ws,         // [ncopy][2][CPAD]
    float* __restrict__ out,
    int nclass, int feat, int batch, int ncopy)
{
    float acc = 0.0f;
    const float inv_feat = 1.0f / (float)feat;
    for (int j = threadIdx.x; j < nclass; j += 256) {
        float s = 0.0f;
        float n = 0.0f;
        for (int c = 0; c < ncopy; ++c) {
            s += ws[(size_t)c * (2 * CPAD) + j];          // coalesced over j
            n += ws[(size_t)c * (2 * CPAD) + CPAD + j];
        }
        if (n > 0.0f) acc += s / n * inv_feat;
    }

    // wave reduce
#pragma unroll
    for (int off = 32; off > 0; off >>= 1)
        acc += __shfl_down(acc, off, WAVE);

    __shared__ float warp_part[4];
    const int lane = threadIdx.x & 63;
    const int wid  = threadIdx.x >> 6;
    if (lane == 0) warp_part[wid] = acc;
    __syncthreads();

    if (threadIdx.x == 0) {
        float total = warp_part[0] + warp_part[1] + warp_part[2] + warp_part[3];
        out[0] = total / (float)batch;
    }
}

extern "C" void kernel_launch(void* const* d_in, const int* in_sizes, int n_in,
                              void* d_out, int out_size, void* d_ws, size_t ws_size,
                              hipStream_t stream) {
    const float* features = (const float*)d_in[0];
    const float* centers  = (const float*)d_in[1];
    const int*   labels   = (const int*)d_in[2];

    const int batch  = in_sizes[2];                 // 65536
    const int feat   = in_sizes[0] / batch;         // 512
    const int nclass = in_sizes[1] / feat;          // 1000

    // Size the privatization factor against the workspace (power of two).
    const size_t copy_bytes = (size_t)(2 * CPAD) * sizeof(float);   // 8 KB
    int ncopy = MAX_COPIES;
    while (ncopy > 1 && (size_t)ncopy * copy_bytes > ws_size) ncopy >>= 1;

    // zero the accumulators (ws is poisoned before every call)
    hipMemsetAsync(d_ws, 0, (size_t)ncopy * copy_bytes, stream);

    // 2048 blocks * 4 waves = 8192 waves = 8 waves/SIMD device-wide;
    // each wave grid-strides over 8 samples.
    int blocks = 2048;
    const int max_blocks = (batch + 3) / 4;
    if (blocks > max_blocks) blocks = max_blocks;

    center_dist_kernel<<<blocks, 256, 0, stream>>>(
        features, centers, labels, (float*)d_ws, batch, feat, ncopy);

    center_finalize_kernel<<<1, 256, 0, stream>>>(
        (const float*)d_ws, (float*)d_out, nclass, feat, batch, ncopy);
}

// Round 2
// 205.413 us; speedup vs baseline: 1.2596x; 1.2596x over previous
//
#include <hip/hip_runtime.h>

// CenterLoss: loss = (1/B) * sum_j [ sum_{i: l_i=j} ||f_i - c_j||^2 / (n_j * D) ]
// B=65536, D=512, C=1000, fp32 in / fp32 scalar out. Memory-bound:
// 128 MiB features + 2 MiB centers + 0.25 MiB labels -> roofline ~21 us @ 6.3 TB/s.
//
// v3: revert to one-wave-per-sample full grid (v1 structure, max TLP) but keep
// v2's 64-way privatized atomic accumulators (spreads 262k fp32 RMWs over
// ~8000 cache lines instead of ~126 -> ~16 serialized RMWs/line).
// Finalize rewritten: 1024 threads (one per class, 16 waves of TLP) instead of
// v2's single-block 256-thread serial load chain, which was a latency-bound
// tail reading 512 KB of atomic-dirtied lines on one CU.

#define WAVE 64
#define CPAD 1024           // padded per-class stride (>= nclass=1000)
#define MAX_COPIES 64       // 64 * 2 * CPAD * 4B = 512 KB workspace

// One wave per sample. Lanes cooperatively load the sample row + its center row
// as float4 (coalesced, 16B/lane), butterfly-reduce the squared distance,
// lane 0 atomically accumulates into this wave's private accumulator copy.
__global__ __launch_bounds__(256) void center_dist_kernel(
    const float* __restrict__ features,   // [batch, feat]
    const float* __restrict__ centers,    // [nclass, feat]
    const int*   __restrict__ labels,     // [batch]
    float* __restrict__ ws,               // [ncopy][2][CPAD]: sums then counts
    int batch, int feat, int ncopy)       // ncopy is a power of two
{
    const int wave_in_block = threadIdx.x >> 6;          // 0..3
    const int lane          = threadIdx.x & 63;
    const int wave_id       = blockIdx.x * 4 + wave_in_block;
    if (wave_id >= batch) return;
    const int sample        = wave_id;

    const int label = labels[sample];

    // Private accumulator copy: spreads atomic traffic over ncopy*~126 lines.
    float* __restrict__ my = ws + (size_t)(wave_id & (ncopy - 1)) * (2 * CPAD);

    const float4* __restrict__ f4 =
        (const float4*)(features + (size_t)sample * feat);
    const float4* __restrict__ c4 =
        (const float4*)(centers + (size_t)label * feat);

    // feat=512 -> 128 float4 per row -> 2 per lane
    float acc = 0.0f;
    const int n4 = feat >> 2;                            // 128
#pragma unroll 2
    for (int idx = lane; idx < n4; idx += WAVE) {
        float4 fv = f4[idx];
        float4 cv = c4[idx];
        float dx = fv.x - cv.x;
        float dy = fv.y - cv.y;
        float dz = fv.z - cv.z;
        float dw = fv.w - cv.w;
        acc += dx * dx + dy * dy;
        acc += dz * dz + dw * dw;
    }

    // wave-64 butterfly reduce
#pragma unroll
    for (int off = 32; off > 0; off >>= 1)
        acc += __shfl_down(acc, off, WAVE);

    if (lane == 0) {
        atomicAdd(&my[label], acc);
        atomicAdd(&my[CPAD + label], 1.0f);
    }
}

// Single block, 1024 threads: thread j owns class j (1000 active). Collapses
// the ncopy privatized copies (coalesced across threads for each copy), then
// block-reduces sum_j s_j/(n_j*feat) and writes the scalar.
__global__ __launch_bounds__(1024) void center_finalize_kernel(
    const float* __restrict__ ws,         // [ncopy][2][CPAD]
    float* __restrict__ out,
    int nclass, int feat, int batch, int ncopy)
{
    const int j = threadIdx.x;
    float term = 0.0f;
    if (j < nclass) {
        float s = 0.0f;
        float n = 0.0f;
#pragma unroll 4
        for (int c = 0; c < ncopy; ++c) {
            const float* __restrict__ cp = ws + (size_t)c * (2 * CPAD);
            s += cp[j];                    // coalesced over j
            n += cp[CPAD + j];
        }
        if (n > 0.0f) term = s / (n * (float)feat);
    }

    // wave reduce
#pragma unroll
    for (int off = 32; off > 0; off >>= 1)
        term += __shfl_down(term, off, WAVE);

    __shared__ float warp_part[16];
    const int lane = threadIdx.x & 63;
    const int wid  = threadIdx.x >> 6;
    if (lane == 0) warp_part[wid] = term;
    __syncthreads();

    if (threadIdx.x < WAVE) {
        float v = (threadIdx.x < 16) ? warp_part[threadIdx.x] : 0.0f;
#pragma unroll
        for (int off = 8; off > 0; off >>= 1)
            v += __shfl_down(v, off, WAVE);
        if (threadIdx.x == 0) out[0] = v / (float)batch;
    }
}

extern "C" void kernel_launch(void* const* d_in, const int* in_sizes, int n_in,
                              void* d_out, int out_size, void* d_ws, size_t ws_size,
                              hipStream_t stream) {
    const float* features = (const float*)d_in[0];
    const float* centers  = (const float*)d_in[1];
    const int*   labels   = (const int*)d_in[2];

    const int batch  = in_sizes[2];                 // 65536
    const int feat   = in_sizes[0] / batch;         // 512
    const int nclass = in_sizes[1] / feat;          // 1000

    // Size the privatization factor against the workspace (power of two).
    const size_t copy_bytes = (size_t)(2 * CPAD) * sizeof(float);   // 8 KB
    int ncopy = MAX_COPIES;
    while (ncopy > 1 && (size_t)ncopy * copy_bytes > ws_size) ncopy >>= 1;

    // zero the accumulators (ws is poisoned before every call)
    hipMemsetAsync(d_ws, 0, (size_t)ncopy * copy_bytes, stream);

    const int blocks = (batch + 3) / 4;             // 4 waves (samples) per block
    center_dist_kernel<<<blocks, 256, 0, stream>>>(
        features, centers, labels, (float*)d_ws, batch, feat, ncopy);

    center_finalize_kernel<<<1, 1024, 0, stream>>>(
        (const float*)d_ws, (float*)d_out, nclass, feat, batch, ncopy);
}